// Round 2
// baseline (293.745 us; speedup 1.0000x reference)
//
#include <hip/hip_runtime.h>

// Channel-combination tree (SELECT matrix) as count + index tables.
__device__ __constant__ int d_cnt[30] = {
    6,6,6,6, 2,2,2,2, 2,2,2,2, 2,2,2,2, 2,2, 3,3,3,3,3,3, 1,1, 2,2, 3,3
};
__device__ __constant__ int d_idx[30][6] = {
    {0,29,42,51,54,63},{0,29,42,51,54,63},{1,30,43,52,55,64},{2,31,44,53,56,65},
    {3,57,0,0,0,0},{4,58,0,0,0,0},{5,45,0,0,0,0},{6,46,0,0,0,0},
    {7,59,0,0,0,0},{8,60,0,0,0,0},{9,47,0,0,0,0},{10,48,0,0,0,0},
    {11,61,0,0,0,0},{12,62,0,0,0,0},{13,49,0,0,0,0},{14,50,0,0,0,0},
    {15,66,0,0,0,0},{16,67,0,0,0,0},{17,32,68,0,0,0},{18,33,69,0,0,0},
    {19,34,70,0,0,0},{20,35,71,0,0,0},{21,36,72,0,0,0},{22,37,73,0,0,0},
    {23,0,0,0,0,0},{24,0,0,0,0,0},{25,38,0,0,0,0},{26,39,0,0,0,0},
    {27,40,74,0,0,0},{28,41,75,0,0,0}
};

// Kernel 1: one net per blockIdx.y, 256 rows per blockIdx.x tile, 1 row/thread.
// All weight accesses are wave-uniform -> scalar (s_load) path; the inner loop
// is v_fmac_f32 acc[k], s_w2, v_h1 with acc[64] resident in VGPRs.
__global__ __launch_bounds__(256) void mlp_kernel(
    const float* __restrict__ t_p,
    const float* __restrict__ comp,
    const float* __restrict__ W1, const float* __restrict__ b1,
    const float* __restrict__ W2, const float* __restrict__ b2,
    const float* __restrict__ W3, const float* __restrict__ b3,
    float* __restrict__ tau_all, int B)
{
    const int n   = blockIdx.y;
    const int row = blockIdx.x * 256 + threadIdx.x;

    const float2 tp = reinterpret_cast<const float2*>(t_p)[row];

    const float* __restrict__ w1  = W1 + n * 2 * 64;   // [2][64]
    const float* __restrict__ bb1 = b1 + n * 64;
    const float* __restrict__ w2  = W2 + n * 64 * 64;  // [64][64]
    const float* __restrict__ bb2 = b2 + n * 64;
    const float* __restrict__ w3  = W3 + n * 64;       // [64]

    float acc[64];
#pragma unroll
    for (int k = 0; k < 64; ++k) acc[k] = 0.0f;

#pragma unroll 4
    for (int h = 0; h < 64; ++h) {
        // first layer, one hidden unit at a time (stays in one VGPR)
        float h1 = fmaf(tp.x, w1[h], fmaf(tp.y, w1[64 + h], bb1[h]));
        h1 = fmaxf(h1, 0.0f);
        const float* __restrict__ w2row = w2 + h * 64;  // contiguous 256B -> s_load_dwordx16 x4
#pragma unroll
        for (int k = 0; k < 64; ++k) {
            acc[k] = fmaf(h1, w2row[k], acc[k]);
        }
    }

    // second-layer bias+relu fused directly into the W3 contraction
    float ke = b3[n];
#pragma unroll
    for (int k = 0; k < 64; ++k) {
        float h2 = fmaxf(acc[k] + bb2[k], 0.0f);
        ke = fmaf(h2, w3[k], ke);
    }
    ke = fmaxf(ke, 0.0f);

    const int gas = (n < 29) ? 0 : (n < 42) ? 1 : (n < 51) ? 2
                  : (n < 54) ? 3 : (n < 63) ? 4 : 5;
    tau_all[n * B + row] = ke * comp[gas * B + row];
}

// Kernel 2: channel combine + lw/iw heads. blockIdx.y = channel c.
__global__ __launch_bounds__(256) void combine_kernel(
    const float* __restrict__ tau_all,
    const float* __restrict__ comp,
    const float* __restrict__ null_lw, const float* __restrict__ null_iw,
    const float* __restrict__ W_lw, const float* __restrict__ b_lw,
    const float* __restrict__ W_iw, const float* __restrict__ b_iw,
    float* __restrict__ out, int B)
{
    const int c   = blockIdx.y;
    const int row = blockIdx.x * 256 + threadIdx.x;

    const int cnt = d_cnt[c];
    float s = 0.0f;
    for (int j = 0; j < cnt; ++j) {
        s += tau_all[d_idx[c][j] * B + row];
    }
    out[c * B + row] = s;

    const float lw = fmaxf(fmaf(null_lw[row], W_lw[c], b_lw[c]), 0.0f) * comp[6 * B + row];
    const float iw = fmaxf(fmaf(null_iw[row], W_iw[c], b_iw[c]), 0.0f) * comp[7 * B + row];
    out[30 * B + c * B + row] = lw;
    out[60 * B + c * B + row] = iw;
}

extern "C" void kernel_launch(void* const* d_in, const int* in_sizes, int n_in,
                              void* d_out, int out_size, void* d_ws, size_t ws_size,
                              hipStream_t stream)
{
    const float* t_p     = (const float*)d_in[0];
    const float* comp    = (const float*)d_in[1];   // [8, B, 1]
    const float* null_lw = (const float*)d_in[2];
    const float* null_iw = (const float*)d_in[3];
    const float* W1      = (const float*)d_in[4];
    const float* b1      = (const float*)d_in[5];
    const float* W2      = (const float*)d_in[6];
    const float* b2      = (const float*)d_in[7];
    const float* W3      = (const float*)d_in[8];
    const float* b3      = (const float*)d_in[9];
    const float* W_lw    = (const float*)d_in[10];
    const float* b_lw    = (const float*)d_in[11];
    const float* W_iw    = (const float*)d_in[12];
    const float* b_iw    = (const float*)d_in[13];
    float* out = (float*)d_out;

    const int B = in_sizes[0] / 2;        // 32768
    float* tau_all = (float*)d_ws;        // 76*B floats = ~10 MB

    dim3 g1(B / 256, 76);
    mlp_kernel<<<g1, dim3(256), 0, stream>>>(
        t_p, comp, W1, b1, W2, b2, W3, b3, tau_all, B);

    dim3 g2(B / 256, 30);
    combine_kernel<<<g2, dim3(256), 0, stream>>>(
        tau_all, comp, null_lw, null_iw, W_lw, b_lw, W_iw, b_iw, out, B);
}

// Round 5
// 225.864 us; speedup vs baseline: 1.3005x; 1.3005x over previous
//
#include <hip/hip_runtime.h>
#include <stdint.h>

typedef __attribute__((ext_vector_type(8)))  short    short8;
typedef __attribute__((ext_vector_type(16))) float    f32x16;
typedef __attribute__((ext_vector_type(4)))  float    f32x4;
typedef __attribute__((ext_vector_type(4)))  uint32_t u32x4;

// net -> gas id (0..5)
__device__ __constant__ int8_t g_gas[76] = {
  0,0,0,0,0,0,0,0,0,0,0,0,0,0,0,0,0,0,0,0,0,0,0,0,0,0,0,0,0,   // h2o 29
  1,1,1,1,1,1,1,1,1,1,1,1,1,                                    // o3 13
  2,2,2,2,2,2,2,2,2,                                            // co2 9
  3,3,3,                                                        // n2o 3
  4,4,4,4,4,4,4,4,4,                                            // ch4 9
  5,5,5,5,5,5,5,5,5,5,5,5,5                                     // u 13
};
// net -> first channel, second channel (-1 = none). Inverse of the SELECT tree.
__device__ __constant__ int8_t g_ch0[76] = {
  0,2,3,4,5,6,7,8,9,10,11,12,13,14,15,16,17,18,19,20,21,22,23,24,25,26,27,28,29,
  0,2,3,18,19,20,21,22,23,26,27,28,29,
  0,2,3,6,7,10,11,14,15,
  0,2,3,
  0,2,3,4,5,8,9,12,13,
  0,2,3,16,17,18,19,20,21,22,23,28,29
};
__device__ __constant__ int8_t g_ch1[76] = {
  1,-1,-1,-1,-1,-1,-1,-1,-1,-1,-1,-1,-1,-1,-1,-1,-1,-1,-1,-1,-1,-1,-1,-1,-1,-1,-1,-1,-1,
  1,-1,-1,-1,-1,-1,-1,-1,-1,-1,-1,-1,-1,
  1,-1,-1,-1,-1,-1,-1,-1,-1,
  1,-1,-1,
  1,-1,-1,-1,-1,-1,-1,-1,-1,
  1,-1,-1,-1,-1,-1,-1,-1,-1,-1,-1,-1,-1
};

// round-to-nearest-even f32 -> bf16 (low 16 bits of result); finite inputs.
__device__ inline uint32_t bf16_rn(float x) {
  uint32_t u = __builtin_bit_cast(uint32_t, x);
  return (u + 0x7fffu + ((u >> 16) & 1u)) >> 16;
}
__device__ inline uint32_t pk2(float a, float b) {
  return bf16_rn(a) | (bf16_rn(b) << 16);
}

// ---------------------------------------------------------------------------
// Prep: split W2 into hi/lo bf16 and lay out as 32x32x16 A-fragments (W2^T).
// Layout: w2f[((i*2 + term)*2 + T)*4 + s][lane][4 words] (u32x4 units)
//   lane l: m = (l&31) + 32*T,  k = 4*(l>>5) + {0,1,2,3,8,9,10,11} + 16*s
// ---------------------------------------------------------------------------
__global__ __launch_bounds__(256) void prep_w2(const float* __restrict__ W2,
                                               u32x4* __restrict__ w2f)
{
  const int i   = blockIdx.x;
  const int tid = threadIdx.x;
  const int l   = tid & 63;
  const int T   = (tid >> 6) & 1;
  const int sh  = tid >> 7;          // 0,1
  const int h   = l >> 5;
  const int m   = (l & 31) + 32 * T;
  const float* __restrict__ w2 = W2 + i * 4096;   // [k][m] row-major
  u32x4* __restrict__ dst = w2f + (size_t)i * 1024;

#pragma unroll
  for (int ss = 0; ss < 2; ++ss) {
    const int s  = sh * 2 + ss;
    const int kb = 4 * h + 16 * s;
    float x[8];
#pragma unroll
    for (int j = 0; j < 4; ++j) x[j]     = w2[(kb + j) * 64 + m];
#pragma unroll
    for (int j = 0; j < 4; ++j) x[4 + j] = w2[(kb + 8 + j) * 64 + m];
    u32x4 hv, lv;
#pragma unroll
    for (int w = 0; w < 4; ++w) {
      float a = x[2 * w], b = x[2 * w + 1];
      uint32_t hp = pk2(a, b);
      float fa = __builtin_bit_cast(float, hp << 16);
      float fb = __builtin_bit_cast(float, hp & 0xffff0000u);
      hv[w] = hp;
      lv[w] = pk2(a - fa, b - fb);
    }
    dst[((0 * 2 + T) * 4 + s) * 64 + l] = hv;
    dst[((1 * 2 + T) * 4 + s) * 64 + l] = lv;
  }
}

// ---------------------------------------------------------------------------
// Fused MLP + channel combine.
// Block: 256 thr = 4 waves = {net-group g in 0..1} x {row-tile t in 0..1}.
// Wave: 32 rows (n = l&31), nets g, g+2, ... (38 nets).
// W2 GEMM transposed: D[h2_m][row] = sum_k W2t_hi/lo[m][k] * h1_hi/lo[k][row]
// via 3-term Dekker split, mfma_f32_32x32x16_bf16.
// ---------------------------------------------------------------------------
__global__ __launch_bounds__(256) void fused_mlp(
    const float* __restrict__ t_p,  const float* __restrict__ comp,
    const float* __restrict__ null_lw, const float* __restrict__ null_iw,
    const float* __restrict__ W1,   const float* __restrict__ b1,
    const float* __restrict__ b2,   const float* __restrict__ W3,
    const float* __restrict__ b3,
    const float* __restrict__ W_lw, const float* __restrict__ b_lw,
    const float* __restrict__ W_iw, const float* __restrict__ b_iw,
    const u32x4* __restrict__ w2f,
    float* __restrict__ out, int B)
{
  __shared__ float chan[2][30][64];
  const int tid = threadIdx.x;
  const int l   = tid & 63;
  const int wv  = tid >> 6;
  const int g   = wv & 1;
  const int t   = wv >> 1;
  const int h   = l >> 5;
  const int ln  = l & 31;
  const int rowBase = blockIdx.x * 64;
  const int row = rowBase + t * 32 + ln;

  for (int i = tid; i < 2 * 30 * 64; i += 256) ((float*)chan)[i] = 0.f;
  __syncthreads();

  const float2 tp = reinterpret_cast<const float2*>(t_p)[row];

  for (int i = g; i < 76; i += 2) {
    // ---- A-fragments (prepped W2^T hi/lo): 16 coalesced dwordx4 loads
    u32x4 Ah[2][4], Al[2][4];
    const u32x4* __restrict__ pnet = w2f + (size_t)i * 1024;
#pragma unroll
    for (int T = 0; T < 2; ++T)
#pragma unroll
      for (int s = 0; s < 4; ++s) {
        Ah[T][s] = pnet[((0 * 2 + T) * 4 + s) * 64 + l];
        Al[T][s] = pnet[((1 * 2 + T) * 4 + s) * 64 + l];
      }

    // ---- B-fragments: h1 = relu(W1^T tp + b1), Dekker split, frag order
    u32x4 Bh[4], Bl[4];
    const float* __restrict__ w1a = W1 + i * 128;
    const float* __restrict__ w1b = w1a + 64;
    const float* __restrict__ bb1 = b1 + i * 64;
#pragma unroll
    for (int s = 0; s < 4; ++s) {
#pragma unroll
      for (int q = 0; q < 2; ++q) {
        const int k0 = 4 * h + q * 8 + 16 * s;
        f32x4 wa = *reinterpret_cast<const f32x4*>(w1a + k0);
        f32x4 wb = *reinterpret_cast<const f32x4*>(w1b + k0);
        f32x4 bv = *reinterpret_cast<const f32x4*>(bb1 + k0);
        float h0  = fmaxf(fmaf(tp.x, wa[0], fmaf(tp.y, wb[0], bv[0])), 0.f);
        float h1v = fmaxf(fmaf(tp.x, wa[1], fmaf(tp.y, wb[1], bv[1])), 0.f);
        float h2v = fmaxf(fmaf(tp.x, wa[2], fmaf(tp.y, wb[2], bv[2])), 0.f);
        float h3v = fmaxf(fmaf(tp.x, wa[3], fmaf(tp.y, wb[3], bv[3])), 0.f);
        uint32_t p0 = pk2(h0, h1v), p1 = pk2(h2v, h3v);
        float l0 = h0  - __builtin_bit_cast(float, p0 << 16);
        float l1 = h1v - __builtin_bit_cast(float, p0 & 0xffff0000u);
        float l2 = h2v - __builtin_bit_cast(float, p1 << 16);
        float l3 = h3v - __builtin_bit_cast(float, p1 & 0xffff0000u);
        Bh[s][q * 2 + 0] = p0;
        Bh[s][q * 2 + 1] = p1;
        Bl[s][q * 2 + 0] = pk2(l0, l1);
        Bl[s][q * 2 + 1] = pk2(l2, l3);
      }
    }

    // ---- MFMA: acc[T] = Ah.Bh + Ah.Bl + Al.Bh
    f32x16 acc0, acc1;
#pragma unroll
    for (int r = 0; r < 16; ++r) { acc0[r] = 0.f; acc1[r] = 0.f; }
#pragma unroll
    for (int s = 0; s < 4; ++s) {
      short8 bh = __builtin_bit_cast(short8, Bh[s]);
      short8 bl = __builtin_bit_cast(short8, Bl[s]);
      acc0 = __builtin_amdgcn_mfma_f32_32x32x16_bf16(__builtin_bit_cast(short8, Ah[0][s]), bh, acc0, 0, 0, 0);
      acc1 = __builtin_amdgcn_mfma_f32_32x32x16_bf16(__builtin_bit_cast(short8, Ah[1][s]), bh, acc1, 0, 0, 0);
      acc0 = __builtin_amdgcn_mfma_f32_32x32x16_bf16(__builtin_bit_cast(short8, Ah[0][s]), bl, acc0, 0, 0, 0);
      acc1 = __builtin_amdgcn_mfma_f32_32x32x16_bf16(__builtin_bit_cast(short8, Ah[1][s]), bl, acc1, 0, 0, 0);
      acc0 = __builtin_amdgcn_mfma_f32_32x32x16_bf16(__builtin_bit_cast(short8, Al[0][s]), bh, acc0, 0, 0, 0);
      acc1 = __builtin_amdgcn_mfma_f32_32x32x16_bf16(__builtin_bit_cast(short8, Al[1][s]), bh, acc1, 0, 0, 0);
    }

    // ---- epilogue: ke = relu( sum_m relu(h2[m]+b2[m]) * w3[m] + b3 )
    // lane holds D rows m = (r&3) + 8*(r>>2) + 4*h + 32*T for its col (row ln)
    float kpa = 0.f, kpb = 0.f;
#pragma unroll
    for (int T = 0; T < 2; ++T) {
      const float* __restrict__ b2p = b2 + i * 64 + T * 32 + 4 * h;
      const float* __restrict__ w3p = W3 + i * 64 + T * 32 + 4 * h;
#pragma unroll
      for (int p = 0; p < 4; ++p) {
        f32x4 bv  = *reinterpret_cast<const f32x4*>(b2p + p * 8);
        f32x4 wvv = *reinterpret_cast<const f32x4*>(w3p + p * 8);
#pragma unroll
        for (int j = 0; j < 4; ++j) {
          float v = fmaxf((T ? acc1[p * 4 + j] : acc0[p * 4 + j]) + bv[j], 0.f);
          if (p & 1) kpb = fmaf(v, wvv[j], kpb);
          else       kpa = fmaf(v, wvv[j], kpa);
        }
      }
    }
    float kp = kpa + kpb;
    kp += __shfl_xor(kp, 32);
    const float ke  = fmaxf(kp + b3[i], 0.f);
    const float tau = ke * comp[(int)g_gas[i] * B + row];

    if (l < 32) {
      float* cp = &chan[g][0][t * 32 + ln];
      cp[64 * (int)g_ch0[i]] += tau;
      const int c1 = g_ch1[i];
      if (c1 >= 0) cp[64 * c1] += tau;
    }
  }
  __syncthreads();

  // ---- combine + lw/iw heads
  for (int idx = tid; idx < 30 * 64; idx += 256) {
    const int c = idx >> 6, rl = idx & 63;
    const int r = rowBase + rl;
    out[c * B + r] = chan[0][c][rl] + chan[1][c][rl];
    const float lw = fmaxf(fmaf(null_lw[r], W_lw[c], b_lw[c]), 0.f) * comp[6 * B + r];
    const float iw = fmaxf(fmaf(null_iw[r], W_iw[c], b_iw[c]), 0.f) * comp[7 * B + r];
    out[(30 + c) * B + r] = lw;
    out[(60 + c) * B + r] = iw;
  }
}

extern "C" void kernel_launch(void* const* d_in, const int* in_sizes, int n_in,
                              void* d_out, int out_size, void* d_ws, size_t ws_size,
                              hipStream_t stream)
{
  const float* t_p     = (const float*)d_in[0];
  const float* comp    = (const float*)d_in[1];
  const float* null_lw = (const float*)d_in[2];
  const float* null_iw = (const float*)d_in[3];
  const float* W1      = (const float*)d_in[4];
  const float* b1      = (const float*)d_in[5];
  const float* W2      = (const float*)d_in[6];
  const float* b2      = (const float*)d_in[7];
  const float* W3      = (const float*)d_in[8];
  const float* b3      = (const float*)d_in[9];
  const float* W_lw    = (const float*)d_in[10];
  const float* b_lw    = (const float*)d_in[11];
  const float* W_iw    = (const float*)d_in[12];
  const float* b_iw    = (const float*)d_in[13];
  float* out = (float*)d_out;

  const int B = in_sizes[0] / 2;     // 32768
  u32x4* w2f = (u32x4*)d_ws;         // 76 * 16 KB = 1.2 MB

  prep_w2<<<dim3(76), dim3(256), 0, stream>>>(W2, w2f);
  fused_mlp<<<dim3(B / 64), dim3(256), 0, stream>>>(
      t_p, comp, null_lw, null_iw, W1, b1, b2, W3, b3,
      W_lw, b_lw, W_iw, b_iw, w2f, out, B);
}

// Round 7
// 221.137 us; speedup vs baseline: 1.3283x; 1.0214x over previous
//
#include <hip/hip_runtime.h>
#include <stdint.h>

typedef __attribute__((ext_vector_type(8)))  short    short8;
typedef __attribute__((ext_vector_type(16))) float    f32x16;
typedef __attribute__((ext_vector_type(4)))  float    f32x4;
typedef __attribute__((ext_vector_type(4)))  uint32_t u32x4;

// net -> gas id (0..5)
__device__ __constant__ int8_t g_gas[76] = {
  0,0,0,0,0,0,0,0,0,0,0,0,0,0,0,0,0,0,0,0,0,0,0,0,0,0,0,0,0,   // h2o 29
  1,1,1,1,1,1,1,1,1,1,1,1,1,                                    // o3 13
  2,2,2,2,2,2,2,2,2,                                            // co2 9
  3,3,3,                                                        // n2o 3
  4,4,4,4,4,4,4,4,4,                                            // ch4 9
  5,5,5,5,5,5,5,5,5,5,5,5,5                                     // u 13
};
// net -> first channel, second channel (-1 = none). Inverse of the SELECT tree.
__device__ __constant__ int8_t g_ch0[76] = {
  0,2,3,4,5,6,7,8,9,10,11,12,13,14,15,16,17,18,19,20,21,22,23,24,25,26,27,28,29,
  0,2,3,18,19,20,21,22,23,26,27,28,29,
  0,2,3,6,7,10,11,14,15,
  0,2,3,
  0,2,3,4,5,8,9,12,13,
  0,2,3,16,17,18,19,20,21,22,23,28,29
};
__device__ __constant__ int8_t g_ch1[76] = {
  1,-1,-1,-1,-1,-1,-1,-1,-1,-1,-1,-1,-1,-1,-1,-1,-1,-1,-1,-1,-1,-1,-1,-1,-1,-1,-1,-1,-1,
  1,-1,-1,-1,-1,-1,-1,-1,-1,-1,-1,-1,-1,
  1,-1,-1,-1,-1,-1,-1,-1,-1,
  1,-1,-1,
  1,-1,-1,-1,-1,-1,-1,-1,-1,
  1,-1,-1,-1,-1,-1,-1,-1,-1,-1,-1,-1,-1
};

// packed f32x2 -> bf16x2 (RTNE), single VALU instruction. Low half = a.
__device__ inline uint32_t cvtpk(float a, float b) {
  uint32_t r;
  asm("v_cvt_pk_bf16_f32 %0, %1, %2" : "=v"(r) : "v"(a), "v"(b));
  return r;
}

// ---------------------------------------------------------------------------
// Prep: split W2 into hi/lo bf16 and lay out as 32x32x16 A-fragments (W2^T).
// Layout: w2f[((term*2 + T)*4 + s)*64 + lane] (u32x4 units), per net i.
//   lane l: m = (l&31) + 32*T,  k = 4*(l>>5) + {0,1,2,3,8,9,10,11} + 16*s
// ---------------------------------------------------------------------------
__global__ __launch_bounds__(256) void prep_w2(const float* __restrict__ W2,
                                               u32x4* __restrict__ w2f)
{
  const int i   = blockIdx.x;
  const int tid = threadIdx.x;
  const int l   = tid & 63;
  const int T   = (tid >> 6) & 1;
  const int sh  = tid >> 7;          // 0,1
  const int h   = l >> 5;
  const int m   = (l & 31) + 32 * T;
  const float* __restrict__ w2 = W2 + i * 4096;   // [k][m] row-major
  u32x4* __restrict__ dst = w2f + (size_t)i * 1024;

#pragma unroll
  for (int ss = 0; ss < 2; ++ss) {
    const int s  = sh * 2 + ss;
    const int kb = 4 * h + 16 * s;
    float x[8];
#pragma unroll
    for (int j = 0; j < 4; ++j) x[j]     = w2[(kb + j) * 64 + m];
#pragma unroll
    for (int j = 0; j < 4; ++j) x[4 + j] = w2[(kb + 8 + j) * 64 + m];
    u32x4 hv, lv;
#pragma unroll
    for (int w = 0; w < 4; ++w) {
      float a = x[2 * w], b = x[2 * w + 1];
      uint32_t hp = cvtpk(a, b);
      float fa = __builtin_bit_cast(float, hp << 16);
      float fb = __builtin_bit_cast(float, hp & 0xffff0000u);
      hv[w] = hp;
      lv[w] = cvtpk(a - fa, b - fb);
    }
    dst[((0 * 2 + T) * 4 + s) * 64 + l] = hv;
    dst[((1 * 2 + T) * 4 + s) * 64 + l] = lv;
  }
}

// ---------------------------------------------------------------------------
// Fused MLP + channel combine.
// Block: 256 thr = 4 waves; wave g handles nets {g, g+4, ...} (19 nets)
// for the SAME 32 rows (rowBase..rowBase+31). Grid = B/32 = 1024 blocks
// -> 4 blocks/CU -> 4 waves/SIMD (launch_bounds caps regs at 128).
// ---------------------------------------------------------------------------
__global__ __launch_bounds__(256, 4) void fused_mlp(
    const float* __restrict__ t_p,  const float* __restrict__ comp,
    const float* __restrict__ null_lw, const float* __restrict__ null_iw,
    const float* __restrict__ W1,   const float* __restrict__ b1,
    const float* __restrict__ b2,   const float* __restrict__ W3,
    const float* __restrict__ b3,
    const float* __restrict__ W_lw, const float* __restrict__ b_lw,
    const float* __restrict__ W_iw, const float* __restrict__ b_iw,
    const u32x4* __restrict__ w2f,
    float* __restrict__ out, int B)
{
  __shared__ float chan[4][30][32];
  const int tid = threadIdx.x;
  const int l   = tid & 63;
  const int g   = tid >> 6;          // wave id = net group
  const int h   = l >> 5;
  const int ln  = l & 31;
  const int rowBase = blockIdx.x * 32;
  const int row = rowBase + ln;

  for (int i = tid; i < 4 * 30 * 32; i += 256) ((float*)chan)[i] = 0.f;
  __syncthreads();

  const float2 tp = reinterpret_cast<const float2*>(t_p)[row];

  for (int i = g; i < 76; i += 4) {
    const u32x4* __restrict__ pnet = w2f + (size_t)i * 1024;

    // ---- B-fragments: h1 = relu(W1^T tp + b1), Dekker split, frag order
    u32x4 Bh[4], Bl[4];
    const float* __restrict__ w1a = W1 + i * 128;
    const float* __restrict__ w1b = w1a + 64;
    const float* __restrict__ bb1 = b1 + i * 64;
#pragma unroll
    for (int s = 0; s < 4; ++s) {
#pragma unroll
      for (int q = 0; q < 2; ++q) {
        const int k0 = 4 * h + q * 8 + 16 * s;
        f32x4 wa = *reinterpret_cast<const f32x4*>(w1a + k0);
        f32x4 wb = *reinterpret_cast<const f32x4*>(w1b + k0);
        f32x4 bv = *reinterpret_cast<const f32x4*>(bb1 + k0);
        float h0  = fmaxf(fmaf(tp.x, wa[0], fmaf(tp.y, wb[0], bv[0])), 0.f);
        float h1v = fmaxf(fmaf(tp.x, wa[1], fmaf(tp.y, wb[1], bv[1])), 0.f);
        float h2v = fmaxf(fmaf(tp.x, wa[2], fmaf(tp.y, wb[2], bv[2])), 0.f);
        float h3v = fmaxf(fmaf(tp.x, wa[3], fmaf(tp.y, wb[3], bv[3])), 0.f);
        uint32_t p0 = cvtpk(h0, h1v), p1 = cvtpk(h2v, h3v);
        float l0 = h0  - __builtin_bit_cast(float, p0 << 16);
        float l1 = h1v - __builtin_bit_cast(float, p0 & 0xffff0000u);
        float l2 = h2v - __builtin_bit_cast(float, p1 << 16);
        float l3 = h3v - __builtin_bit_cast(float, p1 & 0xffff0000u);
        Bh[s][q * 2 + 0] = p0;
        Bh[s][q * 2 + 1] = p1;
        Bl[s][q * 2 + 0] = cvtpk(l0, l1);
        Bl[s][q * 2 + 1] = cvtpk(l2, l3);
      }
    }

    // ---- MFMA: acc[T] = Ah.Bh + Ah.Bl + Al.Bh ; A loaded per-s (16 regs live)
    f32x16 acc0, acc1;
#pragma unroll
    for (int r = 0; r < 16; ++r) { acc0[r] = 0.f; acc1[r] = 0.f; }
#pragma unroll
    for (int s = 0; s < 4; ++s) {
      u32x4 Ah0 = pnet[(0 * 4 + s) * 64 + l];   // term=hi, T=0
      u32x4 Ah1 = pnet[(1 * 4 + s) * 64 + l];   // term=hi, T=1
      u32x4 Al0 = pnet[(2 * 4 + s) * 64 + l];   // term=lo, T=0
      u32x4 Al1 = pnet[(3 * 4 + s) * 64 + l];   // term=lo, T=1
      short8 bh = __builtin_bit_cast(short8, Bh[s]);
      short8 bl = __builtin_bit_cast(short8, Bl[s]);
      acc0 = __builtin_amdgcn_mfma_f32_32x32x16_bf16(__builtin_bit_cast(short8, Ah0), bh, acc0, 0, 0, 0);
      acc1 = __builtin_amdgcn_mfma_f32_32x32x16_bf16(__builtin_bit_cast(short8, Ah1), bh, acc1, 0, 0, 0);
      acc0 = __builtin_amdgcn_mfma_f32_32x32x16_bf16(__builtin_bit_cast(short8, Ah0), bl, acc0, 0, 0, 0);
      acc1 = __builtin_amdgcn_mfma_f32_32x32x16_bf16(__builtin_bit_cast(short8, Ah1), bl, acc1, 0, 0, 0);
      acc0 = __builtin_amdgcn_mfma_f32_32x32x16_bf16(__builtin_bit_cast(short8, Al0), bh, acc0, 0, 0, 0);
      acc1 = __builtin_amdgcn_mfma_f32_32x32x16_bf16(__builtin_bit_cast(short8, Al1), bh, acc1, 0, 0, 0);
    }

    // ---- epilogue: ke = relu( sum_m relu(h2[m]+b2[m]) * w3[m] + b3 )
    // lane holds D rows m = (r&3) + 8*(r>>2) + 4*h + 32*T for its col (row ln)
    float kpa = 0.f, kpb = 0.f;
#pragma unroll
    for (int T = 0; T < 2; ++T) {
      const float* __restrict__ b2p = b2 + i * 64 + T * 32 + 4 * h;
      const float* __restrict__ w3p = W3 + i * 64 + T * 32 + 4 * h;
#pragma unroll
      for (int p = 0; p < 4; ++p) {
        f32x4 bv  = *reinterpret_cast<const f32x4*>(b2p + p * 8);
        f32x4 wvv = *reinterpret_cast<const f32x4*>(w3p + p * 8);
#pragma unroll
        for (int j = 0; j < 4; ++j) {
          float v = fmaxf((T ? acc1[p * 4 + j] : acc0[p * 4 + j]) + bv[j], 0.f);
          if (p & 1) kpb = fmaf(v, wvv[j], kpb);
          else       kpa = fmaf(v, wvv[j], kpa);
        }
      }
    }
    float kp = kpa + kpb;
    kp += __shfl_xor(kp, 32);
    const float ke  = fmaxf(kp + b3[i], 0.f);
    const float tau = ke * comp[(int)g_gas[i] * B + row];

    if (l < 32) {
      float* cp = &chan[g][0][ln];
      cp[32 * (int)g_ch0[i]] += tau;
      const int c1 = g_ch1[i];
      if (c1 >= 0) cp[32 * c1] += tau;
    }
  }
  __syncthreads();

  // ---- combine + lw/iw heads (30 channels x 32 rows)
  for (int idx = tid; idx < 30 * 32; idx += 256) {
    const int c = idx >> 5, rl = idx & 31;
    const int r = rowBase + rl;
    out[c * B + r] = chan[0][c][rl] + chan[1][c][rl] + chan[2][c][rl] + chan[3][c][rl];
    const float lw = fmaxf(fmaf(null_lw[r], W_lw[c], b_lw[c]), 0.f) * comp[6 * B + r];
    const float iw = fmaxf(fmaf(null_iw[r], W_iw[c], b_iw[c]), 0.f) * comp[7 * B + r];
    out[(30 + c) * B + r] = lw;
    out[(60 + c) * B + r] = iw;
  }
}

extern "C" void kernel_launch(void* const* d_in, const int* in_sizes, int n_in,
                              void* d_out, int out_size, void* d_ws, size_t ws_size,
                              hipStream_t stream)
{
  const float* t_p     = (const float*)d_in[0];
  const float* comp    = (const float*)d_in[1];
  const float* null_lw = (const float*)d_in[2];
  const float* null_iw = (const float*)d_in[3];
  const float* W1      = (const float*)d_in[4];
  const float* b1      = (const float*)d_in[5];
  const float* W2      = (const float*)d_in[6];
  const float* b2      = (const float*)d_in[7];
  const float* W3      = (const float*)d_in[8];
  const float* b3      = (const float*)d_in[9];
  const float* W_lw    = (const float*)d_in[10];
  const float* b_lw    = (const float*)d_in[11];
  const float* W_iw    = (const float*)d_in[12];
  const float* b_iw    = (const float*)d_in[13];
  float* out = (float*)d_out;

  const int B = in_sizes[0] / 2;     // 32768
  u32x4* w2f = (u32x4*)d_ws;         // 76 * 16 KB = 1.2 MB

  prep_w2<<<dim3(76), dim3(256), 0, stream>>>(W2, w2f);
  fused_mlp<<<dim3(B / 32), dim3(256), 0, stream>>>(
      t_p, comp, null_lw, null_iw, W1, b1, b2, W3, b3,
      W_lw, b_lw, W_iw, b_iw, w2f, out, B);
}